// Round 10
// baseline (327.262 us; speedup 1.0000x reference)
//
#include <hip/hip_runtime.h>
#include <hip/hip_fp16.h>

#define RAD 40
#define SEGF 16          // output rows per wave-strip
#define TX 256           // output cols per tile
#define HH 1024
#define WW 1024
// Round-10: branchless loads. Evidence (r6-r9): K_A time is invariant
// (~130-150us) across configs while total loads are invariant (~1.38M); per
// wave ~700 cyc/load => MLP ~= 1. Cause: every load was `valid ? load : 0`,
// whose v_cndmask materialization forces s_waitcnt vmcnt(0) per load. Fix:
// clamp addresses into bounds once (clamped lanes read real finite pixels of
// the same row), load unconditionally, apply {0,1} float masks at consume
// time inside the accumulate. Prime loop batches 2 rows (8 loads in flight);
// main-loop prefetches (8 loads) now live across scan+epilogue (enabled by
// r9's wave_fence - no barrier drain).
// History (proven): launch_bounds min-waves>=4 => VGPR=40 + 0.5GB spills
// (r1-4); (.,3) => no spill (r5+). DPP scan beats shfl scan (r6). TX=128
// +13% lane idle (r7). SEGF=32 cuts fetch 36%, time flat (r8). Barrier
// drain removal alone: flat (r9). Field-split (r5), XCD remap (r1): regress.

template<int CTRL, int RMASK>
__device__ __forceinline__ float dpp_add(float v) {
    int t = __builtin_amdgcn_update_dpp(0, __float_as_int(v), CTRL, RMASK, 0xf, false);
    return v + __int_as_float(t);
}

__device__ __forceinline__ float wscan64(float v) {
    v = dpp_add<0x111, 0xf>(v);   // row_shr:1  — intra-16 scan
    v = dpp_add<0x112, 0xf>(v);   // row_shr:2
    v = dpp_add<0x114, 0xf>(v);   // row_shr:4
    v = dpp_add<0x118, 0xf>(v);   // row_shr:8
    v = dpp_add<0x142, 0xa>(v);   // row_bcast:15 -> rows 1,3
    v = dpp_add<0x143, 0xc>(v);   // row_bcast:31 -> rows 2,3
    return v;
}

__device__ __forceinline__ float bcast63(float v) {
    return __int_as_float(__builtin_amdgcn_readlane(__float_as_int(v), 63));
}

// Wave-local fence: ordering only (single independent wave), no vmcnt drain.
__device__ __forceinline__ void wave_fence() {
    asm volatile("" ::: "memory");
    __builtin_amdgcn_wave_barrier();
}

// ---------------------------------------------------------------------------
// K_A: one wave per (channel, x-tile, y-strip). Vertical sliding sums of
// I, p, I*p, I*I in registers; per-row chained DPP scan; writes a,b fp16x2.
// ---------------------------------------------------------------------------
__global__ __launch_bounds__(64, 3)
void fused_ab_kernel(const float* __restrict__ I, const float* __restrict__ p,
                     unsigned int* __restrict__ ab) {
    __shared__ __align__(16) float PF[4][512];
    const int l = threadIdx.x;
    const int bid = blockIdx.x;               // natural dispatch order
    const int strip = bid & 63;
    const int xt = (bid >> 6) & 3;
    const int c = bid >> 8;
    const int x0 = xt * TX;
    const int y0 = strip * SEGF;
    const size_t plane = (size_t)c * (HH * WW);
    const float* Ib = I + plane;
    const float* pb = p + plane;

    const int g1 = x0 - RAD + 4 * l;     // chunk0 col (mult of 4)
    const int g2 = g1 + 256;             // chunk1 col
    // clamped in-bounds addresses (16B-aligned) + {0,1} masks
    const int g1c = (g1 < 0) ? 0 : ((g1 > WW - 4) ? (WW - 4) : g1);
    const int g2c = (g2 > WW - 4) ? (WW - 4) : g2;          // g2 >= 216 always
    const float m1 = ((g1 >= 0) && (g1 < WW)) ? 1.f : 0.f;
    const float m2 = ((l < 20) && (g2 < WW)) ? 1.f : 0.f;

    // vertical sliding sums [field][chunk][k]: 0=I 1=p 2=Ip 3=II
    float s[4][2][4];
    #pragma unroll
    for (int f = 0; f < 4; ++f)
        #pragma unroll
        for (int ch = 0; ch < 2; ++ch)
            #pragma unroll
            for (int k = 0; k < 4; ++k) s[f][ch][k] = 0.f;

    auto ldA = [&](const float* base, int y) -> float4 {
        return *(const float4*)(base + (size_t)y * WW + g1c);
    };
    auto ldB = [&](const float* base, int y) -> float4 {
        return *(const float4*)(base + (size_t)y * WW + g2c);
    };
    // masked accumulate from raw quads (mask folded in at consume time)
    auto accm = [&](float4 iA, float4 iB, float4 pA, float4 pB, float sg) {
        float ri[8] = { iA.x*m1, iA.y*m1, iA.z*m1, iA.w*m1,
                        iB.x*m2, iB.y*m2, iB.z*m2, iB.w*m2 };
        float rp[8] = { pA.x*m1, pA.y*m1, pA.z*m1, pA.w*m1,
                        pB.x*m2, pB.y*m2, pB.z*m2, pB.w*m2 };
        #pragma unroll
        for (int j = 0; j < 8; ++j) {
            const int ch = j >> 2, k = j & 3;
            s[0][ch][k] += sg * ri[j];
            s[1][ch][k] += sg * rp[j];
            s[2][ch][k] += sg * ri[j] * rp[j];
            s[3][ch][k] += sg * ri[j] * ri[j];
        }
    };

    // prime rows [y0-RAD, y0+RAD), 2-row batches: 8 loads in flight
    int yp0 = y0 - RAD; if (yp0 < 0) yp0 = 0;
    int yp1 = y0 + RAD; if (yp1 > HH) yp1 = HH;
    int y = yp0;
    for (; y + 2 <= yp1; y += 2) {
        float4 i0A = ldA(Ib, y    ), i0B = ldB(Ib, y    );
        float4 p0A = ldA(pb, y    ), p0B = ldB(pb, y    );
        float4 i1A = ldA(Ib, y + 1), i1B = ldB(Ib, y + 1);
        float4 p1A = ldA(pb, y + 1), p1B = ldB(pb, y + 1);
        accm(i0A, i0B, p0A, p0B, 1.f);
        accm(i1A, i1B, p1A, p1B, 1.f);
    }
    for (; y < yp1; ++y)
        accm(ldA(Ib, y), ldB(Ib, y), ldA(pb, y), ldB(pb, y), 1.f);

    float4 piA = make_float4(0.f,0.f,0.f,0.f), piB = piA, pqA = piA, pqB = piA;
    if (y0 + RAD < HH) {
        piA = ldA(Ib, y0 + RAD); piB = ldB(Ib, y0 + RAD);
        pqA = ldA(pb, y0 + RAD); pqB = ldB(pb, y0 + RAD);
    }

    for (int yy = y0; yy < y0 + SEGF; ++yy) {
        if (yy + RAD < HH) accm(piA, piB, pqA, pqB, 1.f);
        // issue next add-row + this row's sub-row; stay in flight over scan
        float4 niA, niB, nqA, nqB, siA, siB, sqA, sqB;
        const int yn = yy + 1 + RAD;
        const bool nh = (yn < HH) && (yy + 1 < y0 + SEGF);
        if (nh) { niA = ldA(Ib, yn); niB = ldB(Ib, yn);
                  nqA = ldA(pb, yn); nqB = ldB(pb, yn); }
        const int ys = yy - RAD;
        if (ys >= 0) { siA = ldA(Ib, ys); siB = ldB(Ib, ys);
                       sqA = ldA(pb, ys); sqB = ldB(pb, ys); }

        // chained scans (chunk0 then chunk1), prefix -> LDS
        float incl0[4][4];
        #pragma unroll
        for (int f = 0; f < 4; ++f) {
            float c0 = s[f][0][0];
            float c1 = c0 + s[f][0][1];
            float c2 = c1 + s[f][0][2];
            float c3 = c2 + s[f][0][3];
            float t = wscan64(c3);
            float tot0 = bcast63(t);
            float b0 = t - c3;
            float d0 = s[f][1][0];
            float d1 = d0 + s[f][1][1];
            float d2 = d1 + s[f][1][2];
            float d3 = d2 + s[f][1][3];
            float u = wscan64(d3);
            float b1 = tot0 + (u - d3);
            incl0[f][0] = b0 + c0; incl0[f][1] = b0 + c1;
            incl0[f][2] = b0 + c2; incl0[f][3] = b0 + c3;
            ((float4*)PF[f])[l]      = make_float4(incl0[f][0], incl0[f][1], incl0[f][2], incl0[f][3]);
            ((float4*)PF[f])[64 + l] = make_float4(b1 + d0, b1 + d1, b1 + d2, b1 + d3);
        }
        wave_fence();

        int cv_hi = yy + RAD + 1; if (cv_hi > HH) cv_hi = HH;
        int cv_lo = yy - RAD;     if (cv_lo < 0)  cv_lo = 0;
        const float cntV = (float)(cv_hi - cv_lo);

        float4 hi0 = ((const float4*)PF[0])[l + 20];
        float4 hi1 = ((const float4*)PF[1])[l + 20];
        float4 hi2 = ((const float4*)PF[2])[l + 20];
        float4 hi3 = ((const float4*)PF[3])[l + 20];
        const float* h0 = (const float*)&hi0;
        const float* h1 = (const float*)&hi1;
        const float* h2 = (const float*)&hi2;
        const float* h3 = (const float*)&hi3;

        unsigned int outw[4];
        #pragma unroll
        for (int k = 0; k < 4; ++k) {
            const int go = x0 + 4 * l + k;
            float bI  = h0[k] - (incl0[0][k] - s[0][0][k]);
            float bp  = h1[k] - (incl0[1][k] - s[1][0][k]);
            float bIp = h2[k] - (incl0[2][k] - s[2][0][k]);
            float bII = h3[k] - (incl0[3][k] - s[3][0][k]);
            int hlo = go - RAD;     if (hlo < 0)  hlo = 0;
            int hhi = go + RAD + 1; if (hhi > WW) hhi = WW;
            const float ic = 1.f / (cntV * (float)(hhi - hlo));
            float mI = bI*ic, mp = bp*ic, mIp = bIp*ic, mII = bII*ic;
            float cov = mIp - mI * mp;
            float var = mII - mI * mI;
            float aa = cov / (var + 1e-3f);
            float bb = mp - aa * mI;
            __half2 h = __float22half2_rn(make_float2(aa, bb));
            outw[k] = *reinterpret_cast<unsigned int*>(&h);
        }
        ((uint4*)(ab + plane + (size_t)yy * WW))[(x0 >> 2) + l] =
            make_uint4(outw[0], outw[1], outw[2], outw[3]);

        if (ys >= 0) accm(siA, siB, sqA, sqB, -1.f);
        if (nh) { piA = niA; piB = niB; pqA = nqA; pqB = nqB; }
        wave_fence();
    }
}

// ---------------------------------------------------------------------------
// K_B: same structure on packed a,b; epilogue out = mean_a * I + mean_b
// ---------------------------------------------------------------------------
__global__ __launch_bounds__(64, 3)
void fused_out_kernel(const unsigned int* __restrict__ ab, const float* __restrict__ I,
                      float* __restrict__ out) {
    __shared__ __align__(16) float PF[2][512];
    const int l = threadIdx.x;
    const int bid = blockIdx.x;
    const int strip = bid & 63;
    const int xt = (bid >> 6) & 3;
    const int c = bid >> 8;
    const int x0 = xt * TX;
    const int y0 = strip * SEGF;
    const size_t plane = (size_t)c * (HH * WW);
    const unsigned int* abp = ab + plane;

    const int g1 = x0 - RAD + 4 * l;
    const int g2 = g1 + 256;
    const int g1c = (g1 < 0) ? 0 : ((g1 > WW - 4) ? (WW - 4) : g1);
    const int g2c = (g2 > WW - 4) ? (WW - 4) : g2;
    const float m1 = ((g1 >= 0) && (g1 < WW)) ? 1.f : 0.f;
    const float m2 = ((l < 20) && (g2 < WW)) ? 1.f : 0.f;

    float s[2][2][4];
    #pragma unroll
    for (int f = 0; f < 2; ++f)
        #pragma unroll
        for (int ch = 0; ch < 2; ++ch)
            #pragma unroll
            for (int k = 0; k < 4; ++k) s[f][ch][k] = 0.f;

    auto lduA = [&](int y) -> uint4 {
        return *(const uint4*)(abp + (size_t)y * WW + g1c);
    };
    auto lduB = [&](int y) -> uint4 {
        return *(const uint4*)(abp + (size_t)y * WW + g2c);
    };
    // unpack + mask at consume time (clamped lanes read real finite a,b)
    auto accm = [&](uint4 A, uint4 B, float sg) {
        const unsigned int* aw = (const unsigned int*)&A;
        const unsigned int* bw = (const unsigned int*)&B;
        float ra[8], rb[8];
        #pragma unroll
        for (int k = 0; k < 4; ++k) {
            float2 fa = __half22float2(*reinterpret_cast<const __half2*>(&aw[k]));
            float2 fb = __half22float2(*reinterpret_cast<const __half2*>(&bw[k]));
            ra[k] = fa.x * m1; rb[k] = fa.y * m1;
            ra[4+k] = fb.x * m2; rb[4+k] = fb.y * m2;
        }
        #pragma unroll
        for (int j = 0; j < 8; ++j) {
            const int ch = j >> 2, k = j & 3;
            s[0][ch][k] += sg * ra[j];
            s[1][ch][k] += sg * rb[j];
        }
    };

    int yp0 = y0 - RAD; if (yp0 < 0) yp0 = 0;
    int yp1 = y0 + RAD; if (yp1 > HH) yp1 = HH;
    int y = yp0;
    for (; y + 2 <= yp1; y += 2) {
        uint4 A0 = lduA(y    ), B0 = lduB(y    );
        uint4 A1 = lduA(y + 1), B1 = lduB(y + 1);
        accm(A0, B0, 1.f);
        accm(A1, B1, 1.f);
    }
    for (; y < yp1; ++y)
        accm(lduA(y), lduB(y), 1.f);

    uint4 pA = make_uint4(0u,0u,0u,0u), pB = pA;
    if (y0 + RAD < HH) { pA = lduA(y0 + RAD); pB = lduB(y0 + RAD); }

    for (int yy = y0; yy < y0 + SEGF; ++yy) {
        if (yy + RAD < HH) accm(pA, pB, 1.f);
        uint4 nA, nB, sA, sB;
        const int yn = yy + 1 + RAD;
        const bool nh = (yn < HH) && (yy + 1 < y0 + SEGF);
        if (nh) { nA = lduA(yn); nB = lduB(yn); }
        const int ys = yy - RAD;
        if (ys >= 0) { sA = lduA(ys); sB = lduB(ys); }

        float incl0[2][4];
        #pragma unroll
        for (int f = 0; f < 2; ++f) {
            float c0 = s[f][0][0];
            float c1 = c0 + s[f][0][1];
            float c2 = c1 + s[f][0][2];
            float c3 = c2 + s[f][0][3];
            float t = wscan64(c3);
            float tot0 = bcast63(t);
            float b0 = t - c3;
            float d0 = s[f][1][0];
            float d1 = d0 + s[f][1][1];
            float d2 = d1 + s[f][1][2];
            float d3 = d2 + s[f][1][3];
            float u = wscan64(d3);
            float b1 = tot0 + (u - d3);
            incl0[f][0] = b0 + c0; incl0[f][1] = b0 + c1;
            incl0[f][2] = b0 + c2; incl0[f][3] = b0 + c3;
            ((float4*)PF[f])[l]      = make_float4(incl0[f][0], incl0[f][1], incl0[f][2], incl0[f][3]);
            ((float4*)PF[f])[64 + l] = make_float4(b1 + d0, b1 + d1, b1 + d2, b1 + d3);
        }
        wave_fence();

        int cv_hi = yy + RAD + 1; if (cv_hi > HH) cv_hi = HH;
        int cv_lo = yy - RAD;     if (cv_lo < 0)  cv_lo = 0;
        const float cntV = (float)(cv_hi - cv_lo);

        float4 hiA = ((const float4*)PF[0])[l + 20];
        float4 hiB = ((const float4*)PF[1])[l + 20];
        const float* hA = (const float*)&hiA;
        const float* hB = (const float*)&hiB;
        float4 Iv = ((const float4*)(I + plane + (size_t)yy * WW))[(x0 >> 2) + l];
        const float* Ik = (const float*)&Iv;

        float oo[4];
        #pragma unroll
        for (int k = 0; k < 4; ++k) {
            const int go = x0 + 4 * l + k;
            float ba = hA[k] - (incl0[0][k] - s[0][0][k]);
            float bb = hB[k] - (incl0[1][k] - s[1][0][k]);
            int hlo = go - RAD;     if (hlo < 0)  hlo = 0;
            int hhi = go + RAD + 1; if (hhi > WW) hhi = WW;
            const float ic = 1.f / (cntV * (float)(hhi - hlo));
            oo[k] = (ba * ic) * Ik[k] + bb * ic;
        }
        ((float4*)(out + plane + (size_t)yy * WW))[(x0 >> 2) + l] =
            make_float4(oo[0], oo[1], oo[2], oo[3]);

        if (ys >= 0) accm(sA, sB, -1.f);
        if (nh) { pA = nA; pB = nB; }
        wave_fence();
    }
}

extern "C" void kernel_launch(void* const* d_in, const int* in_sizes, int n_in,
                              void* d_out, int out_size, void* d_ws, size_t ws_size,
                              hipStream_t stream) {
    const float* I = (const float*)d_in[0];
    const float* p = (const float*)d_in[1];
    float* out = (float*)d_out;

    const int N = in_sizes[0];           // B*C*H*W
    const int BC = N / (HH * WW);

    unsigned int* ab = (unsigned int*)d_ws;   // fp16x2 {a,b} per pixel

    const int nblk = BC * (WW / TX) * (HH / SEGF);   // BC * 4 * 64
    fused_ab_kernel<<<dim3(nblk), 64, 0, stream>>>(I, p, ab);
    fused_out_kernel<<<dim3(nblk), 64, 0, stream>>>(ab, I, out);
}

// Round 11
// 322.503 us; speedup vs baseline: 1.0148x; 1.0148x over previous
//
#include <hip/hip_runtime.h>
#include <hip/hip_fp16.h>

#define RAD 40
#define SEGF 16          // output rows per wave-strip
#define TX 128           // output cols per tile
#define HH 1024
#define WW 1024
#define NSTRIP 64        // HH/SEGF
#define NXT 8            // WW/TX
// Round-11: 4 INDEPENDENT tiles per 256-thread workgroup. Evidence: residency
// caps at ~10-11 workgroups/CU regardless of grid (r6: offered 12 -> ~10;
// r7: offered 24 -> ~11) while VGPR (9 waves/SIMD possible) and LDS (20+
// blocks) never bind => per-CU WORKGROUP-SLOT limit. Packing 4 waves/slot
// lifts the cap: 6144 waves / 1536 blocks = 6 blocks/CU = 24 waves/CU
// offered, all under VGPR/LDS limits. Waves stay decoupled (no __syncthreads,
// private LDS slice per wave, wave_fence only).
// r10 lesson: branchless clamped loads REGRESSED (all 64 lanes issued the
// 20-lane chunk-B load -> FETCH +38%; time/load unchanged => exec-masked
// ternary loads were never the serializer). Ternary loads restored.
// History (proven): min-waves>=4 @64-thread blocks => 40-VGPR spills (r1-4);
// DPP scan beats shfl (r6); SEGF=32 cuts fetch, time flat (r8); barrier-drain
// removal flat (r9); field-split (r5) and XCD remap (r1) regress.

template<int CTRL, int RMASK>
__device__ __forceinline__ float dpp_add(float v) {
    int t = __builtin_amdgcn_update_dpp(0, __float_as_int(v), CTRL, RMASK, 0xf, false);
    return v + __int_as_float(t);
}

__device__ __forceinline__ float wscan64(float v) {
    v = dpp_add<0x111, 0xf>(v);   // row_shr:1  — intra-16 scan
    v = dpp_add<0x112, 0xf>(v);   // row_shr:2
    v = dpp_add<0x114, 0xf>(v);   // row_shr:4
    v = dpp_add<0x118, 0xf>(v);   // row_shr:8
    v = dpp_add<0x142, 0xa>(v);   // row_bcast:15 -> rows 1,3
    v = dpp_add<0x143, 0xc>(v);   // row_bcast:31 -> rows 2,3
    return v;
}

// Wave-local fence: ordering only (waves are independent), no barrier drain.
__device__ __forceinline__ void wave_fence() {
    asm volatile("" ::: "memory");
    __builtin_amdgcn_wave_barrier();
}

// ---------------------------------------------------------------------------
// K_A: each wave owns one (channel, x-tile, y-strip) tile. Vertical sliding
// sums of I, p, I*p, I*I in registers; per-row single DPP scan; a,b fp16x2.
// ---------------------------------------------------------------------------
__global__ __launch_bounds__(256, 4)
void fused_ab_kernel(const float* __restrict__ I, const float* __restrict__ p,
                     unsigned int* __restrict__ ab) {
    // [wave][field][quad 20..51 of the 64-quad domain] — only what epilogue reads
    __shared__ __align__(16) float4 PFS[4][4][32];
    const int tid = threadIdx.x;
    const int w = tid >> 6;
    const int l = tid & 63;
    const int t = (int)blockIdx.x * 4 + w;    // natural order; waves = adjacent strips
    const int strip = t & (NSTRIP - 1);
    const int xt = (t >> 6) & (NXT - 1);
    const int c = t >> 9;
    const int x0 = xt * TX;
    const int y0 = strip * SEGF;
    const size_t plane = (size_t)c * (HH * WW);
    const float* Ib = I + plane;
    const float* pb = p + plane;

    const int g1 = x0 - RAD + 4 * l;     // domain col (mult of 4)
    const bool v1 = (l < 52) && (g1 >= 0) && (g1 < WW);

    // vertical sliding sums [field][k]: 0=I 1=p 2=Ip 3=II
    float s[4][4];
    #pragma unroll
    for (int f = 0; f < 4; ++f)
        #pragma unroll
        for (int k = 0; k < 4; ++k) s[f][k] = 0.f;

    auto ld = [&](const float* base, int y) -> float4 {
        return v1 ? *(const float4*)(base + (size_t)y * WW + g1)
                  : make_float4(0.f, 0.f, 0.f, 0.f);
    };
    auto acc = [&](float4 a, float4 b, float sg) {
        const float* ri = (const float*)&a;
        const float* rp = (const float*)&b;
        #pragma unroll
        for (int k = 0; k < 4; ++k) {
            s[0][k] += sg * ri[k];
            s[1][k] += sg * rp[k];
            s[2][k] += sg * ri[k] * rp[k];
            s[3][k] += sg * ri[k] * ri[k];
        }
    };

    // prime rows [y0-RAD, y0+RAD)
    int yp0 = y0 - RAD; if (yp0 < 0) yp0 = 0;
    int yp1 = y0 + RAD; if (yp1 > HH) yp1 = HH;
    for (int y = yp0; y < yp1; ++y) {
        float4 a0 = ld(Ib, y), b0 = ld(pb, y);
        acc(a0, b0, 1.f);
    }

    float4 pi = make_float4(0.f,0.f,0.f,0.f), pq = pi;
    if (y0 + RAD < HH) { pi = ld(Ib, y0 + RAD); pq = ld(pb, y0 + RAD); }

    for (int yy = y0; yy < y0 + SEGF; ++yy) {
        if (yy + RAD < HH) acc(pi, pq, 1.f);
        // prefetch next add-row and this row's sub-row (hide under scan)
        float4 ni = make_float4(0.f,0.f,0.f,0.f), nq = ni, si = ni, sq = ni;
        const int yn = yy + 1 + RAD;
        const bool nh = (yn < HH) && (yy + 1 < y0 + SEGF);
        if (nh) { ni = ld(Ib, yn); nq = ld(pb, yn); }
        const int ys = yy - RAD;
        if (ys >= 0) { si = ld(Ib, ys); sq = ld(pb, ys); }

        // single DPP scan per field; store only quads 20..51 (epilogue window)
        float incl0[4][4];
        #pragma unroll
        for (int f = 0; f < 4; ++f) {
            float c0 = s[f][0];
            float c1 = c0 + s[f][1];
            float c2 = c1 + s[f][2];
            float c3 = c2 + s[f][3];
            float ttt = wscan64(c3);
            float b0 = ttt - c3;
            incl0[f][0] = b0 + c0; incl0[f][1] = b0 + c1;
            incl0[f][2] = b0 + c2; incl0[f][3] = b0 + c3;
            if (l >= 20 && l < 52)
                PFS[w][f][l - 20] = make_float4(incl0[f][0], incl0[f][1],
                                                incl0[f][2], incl0[f][3]);
        }
        wave_fence();   // order this wave's LDS writes before its reads

        int cv_hi = yy + RAD + 1; if (cv_hi > HH) cv_hi = HH;
        int cv_lo = yy - RAD;     if (cv_lo < 0)  cv_lo = 0;
        const float cntV = (float)(cv_hi - cv_lo);

        if (l < 32) {   // 32 lanes cover the 128 output cols
            float4 hi0 = PFS[w][0][l];
            float4 hi1 = PFS[w][1][l];
            float4 hi2 = PFS[w][2][l];
            float4 hi3 = PFS[w][3][l];
            const float* h0 = (const float*)&hi0;
            const float* h1 = (const float*)&hi1;
            const float* h2 = (const float*)&hi2;
            const float* h3 = (const float*)&hi3;

            unsigned int outw[4];
            #pragma unroll
            for (int k = 0; k < 4; ++k) {
                const int go = x0 + 4 * l + k;
                float bI  = h0[k] - (incl0[0][k] - s[0][k]);
                float bp  = h1[k] - (incl0[1][k] - s[1][k]);
                float bIp = h2[k] - (incl0[2][k] - s[2][k]);
                float bII = h3[k] - (incl0[3][k] - s[3][k]);
                int hlo = go - RAD;     if (hlo < 0)  hlo = 0;
                int hhi = go + RAD + 1; if (hhi > WW) hhi = WW;
                const float ic = 1.f / (cntV * (float)(hhi - hlo));
                float mI = bI*ic, mp = bp*ic, mIp = bIp*ic, mII = bII*ic;
                float cov = mIp - mI * mp;
                float var = mII - mI * mI;
                float aa = cov / (var + 1e-3f);
                float bbv = mp - aa * mI;
                __half2 h = __float22half2_rn(make_float2(aa, bbv));
                outw[k] = *reinterpret_cast<unsigned int*>(&h);
            }
            ((uint4*)(ab + plane + (size_t)yy * WW))[(x0 >> 2) + l] =
                make_uint4(outw[0], outw[1], outw[2], outw[3]);
        }

        if (ys >= 0) acc(si, sq, -1.f);
        if (nh) { pi = ni; pq = nq; }
        wave_fence();   // order next iter's writes after this iter's reads
    }
}

// ---------------------------------------------------------------------------
// K_B: same packaging on packed a,b; epilogue out = mean_a * I + mean_b
// ---------------------------------------------------------------------------
__global__ __launch_bounds__(256, 4)
void fused_out_kernel(const unsigned int* __restrict__ ab, const float* __restrict__ I,
                      float* __restrict__ out) {
    __shared__ __align__(16) float4 PFS[4][2][32];
    const int tid = threadIdx.x;
    const int w = tid >> 6;
    const int l = tid & 63;
    const int t = (int)blockIdx.x * 4 + w;
    const int strip = t & (NSTRIP - 1);
    const int xt = (t >> 6) & (NXT - 1);
    const int c = t >> 9;
    const int x0 = xt * TX;
    const int y0 = strip * SEGF;
    const size_t plane = (size_t)c * (HH * WW);
    const unsigned int* abp = ab + plane;

    const int g1 = x0 - RAD + 4 * l;
    const bool v1 = (l < 52) && (g1 >= 0) && (g1 < WW);

    float s[2][4];
    #pragma unroll
    for (int f = 0; f < 2; ++f)
        #pragma unroll
        for (int k = 0; k < 4; ++k) s[f][k] = 0.f;

    auto ld2 = [&](int y, float* ra, float* rb) {
        uint4 A = v1 ? *(const uint4*)(abp + (size_t)y * WW + g1)
                     : make_uint4(0u, 0u, 0u, 0u);
        const unsigned int* aw = (const unsigned int*)&A;
        #pragma unroll
        for (int k = 0; k < 4; ++k) {
            float2 f2 = __half22float2(*reinterpret_cast<const __half2*>(&aw[k]));
            ra[k] = f2.x; rb[k] = f2.y;
        }
    };
    auto acc2 = [&](const float* ra, const float* rb, float sg) {
        #pragma unroll
        for (int k = 0; k < 4; ++k) {
            s[0][k] += sg * ra[k];
            s[1][k] += sg * rb[k];
        }
    };

    int yp0 = y0 - RAD; if (yp0 < 0) yp0 = 0;
    int yp1 = y0 + RAD; if (yp1 > HH) yp1 = HH;
    for (int y = yp0; y < yp1; ++y) {
        float ra[4], rb[4];
        ld2(y, ra, rb);
        acc2(ra, rb, 1.f);
    }

    float pa[4] = {0.f,0.f,0.f,0.f}, pbv[4] = {0.f,0.f,0.f,0.f};
    if (y0 + RAD < HH) ld2(y0 + RAD, pa, pbv);

    for (int yy = y0; yy < y0 + SEGF; ++yy) {
        if (yy + RAD < HH) acc2(pa, pbv, 1.f);
        float na[4] = {0.f,0.f,0.f,0.f}, nb[4] = {0.f,0.f,0.f,0.f};
        float sa[4] = {0.f,0.f,0.f,0.f}, sb[4] = {0.f,0.f,0.f,0.f};
        const int yn = yy + 1 + RAD;
        const bool nh = (yn < HH) && (yy + 1 < y0 + SEGF);
        if (nh) ld2(yn, na, nb);
        const int ys = yy - RAD;
        if (ys >= 0) ld2(ys, sa, sb);

        float incl0[2][4];
        #pragma unroll
        for (int f = 0; f < 2; ++f) {
            float c0 = s[f][0];
            float c1 = c0 + s[f][1];
            float c2 = c1 + s[f][2];
            float c3 = c2 + s[f][3];
            float ttt = wscan64(c3);
            float b0 = ttt - c3;
            incl0[f][0] = b0 + c0; incl0[f][1] = b0 + c1;
            incl0[f][2] = b0 + c2; incl0[f][3] = b0 + c3;
            if (l >= 20 && l < 52)
                PFS[w][f][l - 20] = make_float4(incl0[f][0], incl0[f][1],
                                                incl0[f][2], incl0[f][3]);
        }
        wave_fence();

        int cv_hi = yy + RAD + 1; if (cv_hi > HH) cv_hi = HH;
        int cv_lo = yy - RAD;     if (cv_lo < 0)  cv_lo = 0;
        const float cntV = (float)(cv_hi - cv_lo);

        if (l < 32) {
            float4 hiA = PFS[w][0][l];
            float4 hiB = PFS[w][1][l];
            const float* hA = (const float*)&hiA;
            const float* hB = (const float*)&hiB;
            float4 Iv = ((const float4*)(I + plane + (size_t)yy * WW))[(x0 >> 2) + l];
            const float* Ik = (const float*)&Iv;

            float oo[4];
            #pragma unroll
            for (int k = 0; k < 4; ++k) {
                const int go = x0 + 4 * l + k;
                float ba = hA[k] - (incl0[0][k] - s[0][k]);
                float bb = hB[k] - (incl0[1][k] - s[1][k]);
                int hlo = go - RAD;     if (hlo < 0)  hlo = 0;
                int hhi = go + RAD + 1; if (hhi > WW) hhi = WW;
                const float ic = 1.f / (cntV * (float)(hhi - hlo));
                oo[k] = (ba * ic) * Ik[k] + bb * ic;
            }
            ((float4*)(out + plane + (size_t)yy * WW))[(x0 >> 2) + l] =
                make_float4(oo[0], oo[1], oo[2], oo[3]);
        }

        if (ys >= 0) acc2(sa, sb, -1.f);
        if (nh) {
            #pragma unroll
            for (int k = 0; k < 4; ++k) { pa[k] = na[k]; pbv[k] = nb[k]; }
        }
        wave_fence();
    }
}

extern "C" void kernel_launch(void* const* d_in, const int* in_sizes, int n_in,
                              void* d_out, int out_size, void* d_ws, size_t ws_size,
                              hipStream_t stream) {
    const float* I = (const float*)d_in[0];
    const float* p = (const float*)d_in[1];
    float* out = (float*)d_out;

    const int N = in_sizes[0];           // B*C*H*W
    const int BC = N / (HH * WW);

    unsigned int* ab = (unsigned int*)d_ws;   // fp16x2 {a,b} per pixel

    const int ntile = BC * NXT * NSTRIP;      // BC * 8 * 64 = 6144 wave-tiles
    const int nblk = ntile / 4;               // 4 waves per workgroup
    fused_ab_kernel<<<dim3(nblk), 256, 0, stream>>>(I, p, ab);
    fused_out_kernel<<<dim3(nblk), 256, 0, stream>>>(ab, I, out);
}